// Round 5
// baseline (289.155 us; speedup 1.0000x reference)
//
#include <hip/hip_runtime.h>
#include <hip/hip_bf16.h>

typedef unsigned short u16;

#define B_      8
#define N_      1025
#define D_      768
#define H_      12
#define HD_     64
#define M_REAL  (B_ * N_)      /* 8200 rows */
#define M_PAD   8320           /* 65 * 128 */
#define QKVC    (3 * D_)       /* 2304 */
#define LN_BLK  (M_REAL / 4)   /* 2050 wave-per-row blocks */

typedef __attribute__((ext_vector_type(8))) short bf16x8;
typedef __attribute__((ext_vector_type(4))) float f32x4;

static __device__ __forceinline__ float bf2f(u16 u) {
    union { unsigned int i; float f; } v; v.i = ((unsigned int)u) << 16; return v.f;
}
static __device__ __forceinline__ u16 f2bf(float f) {
    union { float f; unsigned int i; } v; v.f = f;
    unsigned int x = v.i;
    return (u16)((x + 0x7fffu + ((x >> 16) & 1u)) >> 16);   /* RNE */
}
static __device__ __forceinline__ unsigned int cvtpk(float a, float b) {
    unsigned int r;
    asm volatile("v_cvt_pk_bf16_f32 %0, %1, %2" : "=v"(r) : "v"(a), "v"(b));
    return r;   /* lo = bf16(a), hi = bf16(b) */
}

/* async global->LDS, 16B per lane; LDS dest = wave-uniform base + lane*16 */
static __device__ __forceinline__ void g2l16(const u16* g, u16* l) {
    __builtin_amdgcn_global_load_lds(
        (const __attribute__((address_space(1))) unsigned int*)g,
        (__attribute__((address_space(3))) unsigned int*)l, 16, 0, 0);
}

/* ------- fused LayerNorm (wave per row) + fp32->bf16 weight convert ------- */
__global__ __launch_bounds__(256)
void ln_f2b_kernel(const float* __restrict__ x, const float* __restrict__ g,
                   const float* __restrict__ bvec, u16* __restrict__ xn,
                   const float* __restrict__ wq, u16* __restrict__ wqb,
                   const float* __restrict__ wp, u16* __restrict__ wpb)
{
    const int tid = threadIdx.x;
    if (blockIdx.x >= LN_BLK) {
        /* weight convert: 1024 elems per block */
        int i = (blockIdx.x - LN_BLK) * 1024 + tid * 4;
        const float* src; u16* dst;
        if (i < QKVC * D_) { src = wq + i; dst = wqb + i; }
        else { src = wp + (i - QKVC * D_); dst = wpb + (i - QKVC * D_); }
        float4 v = *(const float4*)src;
        dst[0] = f2bf(v.x); dst[1] = f2bf(v.y);
        dst[2] = f2bf(v.z); dst[3] = f2bf(v.w);
        return;
    }
    /* one wave per row: 768 = 3 * 64 lanes * float4, shuffle reduce, no barrier */
    const int wave = tid >> 6, lane = tid & 63;
    const int row  = blockIdx.x * 4 + wave;          /* < 8200 exactly */
    const float* xr = x + (size_t)row * D_;
    float4 v[3];
    float s = 0.f, ss = 0.f;
#pragma unroll
    for (int j = 0; j < 3; j++) {
        float4 t = *(const float4*)&xr[j * 256 + lane * 4];
        v[j] = t;
        s  += (t.x + t.y) + (t.z + t.w);
        ss += (t.x * t.x + t.y * t.y) + (t.z * t.z + t.w * t.w);
    }
#pragma unroll
    for (int off = 1; off < 64; off <<= 1) {
        s  += __shfl_xor(s,  off);
        ss += __shfl_xor(ss, off);
    }
    const float mean = s * (1.0f / D_);
    const float var  = ss * (1.0f / D_) - mean * mean;
    const float rs   = rsqrtf(var + 1e-5f);
    u16* outr = xn + (size_t)row * D_;
#pragma unroll
    for (int j = 0; j < 3; j++) {
        int c = j * 256 + lane * 4;
        float4 g4 = *(const float4*)&g[c];
        float4 b4 = *(const float4*)&bvec[c];
        u16 o[4];
        o[0] = f2bf((v[j].x - mean) * rs * g4.x + b4.x);
        o[1] = f2bf((v[j].y - mean) * rs * g4.y + b4.y);
        o[2] = f2bf((v[j].z - mean) * rs * g4.z + b4.z);
        o[3] = f2bf((v[j].w - mean) * rs * g4.w + b4.w);
        *(uint2*)&outr[c] = *(const uint2*)o;
    }
}

/* -------- GEMM: C[m][n] = sum_k A[m][k] * B[n][k] (+bias fp32) --------
   r3 version (measured 61.4us QKV): 128x128 tile, BK=32, 4 waves (2x2),
   counted-vmcnt pipeline, 34816 B LDS, pad-based epilogues.             */
template <typename OutT, bool ROPE>
__global__ __launch_bounds__(256)
void gemm_bt(const u16* __restrict__ A, const u16* __restrict__ B,
             OutT* __restrict__ C, const float* __restrict__ bias,
             int M_real, int Ncols, int K,
             int BM, int BN, int gh, int gw, int PC)
{
    const int l   = blockIdx.x;
    const int xcd = l & 7;
    const int i0  = l >> 3;
    const int pr  = xcd / PC, pc = xcd % PC;
    const int bm  = pr * gh + (i0 % gh);
    const int bn  = pc * gw + (i0 / gh);
    if (bm >= BM || bn >= BN) return;

    __shared__ __align__(16) unsigned char smem[34816];
    u16* As0 = (u16*)smem;              /* 128 x 32 */
    u16* Bs0 = (u16*)(smem + 8192);
    u16*   ep16 = (u16*)smem;           /* 128 x 136 (pad 8) */
    float* ep32 = (float*)smem;         /* 64 x 132 (pad 4)  */

    const int tid  = threadIdx.x;
    const int wave = tid >> 6, lane = tid & 63;
    const int wm   = (wave >> 1) * 64, wn = (wave & 1) * 64;
    const int lrow = lane & 15, lq = lane >> 4;
    const int lrow4 = lane >> 2, lchunk = lane & 3;

    int ar0 = bm * 128 + wave * 16 + lrow4;       if (ar0 >= M_real) ar0 = M_real - 1;
    int ar1 = bm * 128 + (wave + 4) * 16 + lrow4; if (ar1 >= M_real) ar1 = M_real - 1;
    const u16* apg0 = A + (size_t)ar0 * K + lchunk * 8;
    const u16* apg1 = A + (size_t)ar1 * K + lchunk * 8;
    const u16* bpg0 = B + (size_t)(bn * 128 + wave * 16 + lrow4) * K + lchunk * 8;
    const u16* bpg1 = B + (size_t)(bn * 128 + (wave + 4) * 16 + lrow4) * K + lchunk * 8;
    u16* asl0 = As0 + wave * 512;       u16* asl1 = As0 + (wave + 4) * 512;
    u16* bsl0 = Bs0 + wave * 512;       u16* bsl1 = Bs0 + (wave + 4) * 512;
    const int bufoff = 8192;

    f32x4 acc[4][4];
#pragma unroll
    for (int i = 0; i < 4; i++)
#pragma unroll
        for (int j = 0; j < 4; j++)
            acc[i][j] = (f32x4){0.f, 0.f, 0.f, 0.f};

    g2l16(apg0, asl0); g2l16(apg1, asl1);
    g2l16(bpg0, bsl0); g2l16(bpg1, bsl1);

    const int kTiles = K / 32;
    for (int kt = 0; kt < kTiles; kt++) {
        const int cur = kt & 1;
        /* issue next tile BEFORE the wait: its 4 loads stay in flight
           across the barrier (counted vmcnt, no full drain).           */
        if (kt + 1 < kTiles) {
            const int k1 = (kt + 1) * 32;
            const int no = (cur ^ 1) * bufoff;
            g2l16(apg0 + k1, asl0 + no); g2l16(apg1 + k1, asl1 + no);
            g2l16(bpg0 + k1, bsl0 + no); g2l16(bpg1 + k1, bsl1 + no);
            asm volatile("s_waitcnt vmcnt(4)" ::: "memory");
        } else {
            asm volatile("s_waitcnt vmcnt(0)" ::: "memory");
        }
        __builtin_amdgcn_s_barrier();      /* current tile visible to all */

        const u16* Asr = As0 + cur * bufoff;
        const u16* Bsr = Bs0 + cur * bufoff;
        bf16x8 af[4], bfr[4];
#pragma unroll
        for (int i = 0; i < 4; i++) {
            af[i]  = *(const bf16x8*)&Asr[(wm + i * 16 + lrow) * 32 + lq * 8];
            bfr[i] = *(const bf16x8*)&Bsr[(wn + i * 16 + lrow) * 32 + lq * 8];
        }
        __builtin_amdgcn_s_setprio(1);
#pragma unroll
        for (int i = 0; i < 4; i++)
#pragma unroll
            for (int j = 0; j < 4; j++)
                acc[i][j] = __builtin_amdgcn_mfma_f32_16x16x32_bf16(af[i], bfr[j], acc[i][j], 0, 0, 0);
        __builtin_amdgcn_s_setprio(0);
        /* all waves done reading buf cur before iter kt+1 overwrites it */
        __builtin_amdgcn_s_barrier();
    }
    __syncthreads();

    if constexpr (sizeof(OutT) == 2) {
#pragma unroll
        for (int j = 0; j < 4; j++) {
            int gcol = bn * 128 + wn + j * 16 + lrow;
            float bv = bias ? bias[gcol] : 0.f;
            int qk = gcol / D_;
            int dh = gcol & 63;
            int half = dh >> 5, ii = (dh & 31) >> 1;
            float sgn = (dh & 1) ? 1.f : -1.f;
            float invf = exp2f(-(float)ii * 0.8304820237218406f);
#pragma unroll
            for (int i = 0; i < 4; i++)
#pragma unroll
                for (int r = 0; r < 4; r++) {
                    int grow = bm * 128 + wm + i * 16 + lq * 4 + r;
                    float val = acc[i][j][r] + bv;
                    if constexpr (ROPE) {
                        if (qk < 2) {
                            float partner = __shfl_xor(val, 1);
                            int n = grow % N_;
                            int pl = n - 1;
                            int pos = (n == 0) ? 0 : (half ? (pl & 31) : (pl >> 5));
                            float ang = (float)pos * invf;
                            val = val * __cosf(ang) + sgn * partner * __sinf(ang);
                            if (qk == 0) val *= 0.125f;   /* fold 1/sqrt(hd) into Q (exact) */
                        }
                    }
                    ep16[(wm + i * 16 + lq * 4 + r) * 136 + wn + j * 16 + lrow] = f2bf(val);
                }
        }
        __syncthreads();
#pragma unroll
        for (int c = 0; c < 8; c++) {
            int idx = tid + c * 256;
            int row = idx >> 4, l16 = idx & 15;
            int grow = bm * 128 + row;
            if (grow < M_real)
                *(uint4*)((u16*)C + (size_t)grow * Ncols + bn * 128 + l16 * 8) =
                    *(const uint4*)&ep16[row * 136 + l16 * 8];
        }
    } else {
#pragma unroll
        for (int s = 0; s < 2; s++) {
            if (s) __syncthreads();
            if (wm == s * 64) {
#pragma unroll
                for (int j = 0; j < 4; j++) {
                    int gcol = bn * 128 + wn + j * 16 + lrow;
                    float bv = bias ? bias[gcol] : 0.f;
#pragma unroll
                    for (int i = 0; i < 4; i++)
#pragma unroll
                        for (int r = 0; r < 4; r++)
                            ep32[(i * 16 + lq * 4 + r) * 132 + wn + j * 16 + lrow] =
                                acc[i][j][r] + bv;
                }
            }
            __syncthreads();
#pragma unroll
            for (int c = 0; c < 8; c++) {
                int idx = tid + c * 256;
                int row = idx >> 5, l32 = idx & 31;
                int grow = bm * 128 + s * 64 + row;
                if (grow < M_real)
                    *(uint4*)((float*)C + (size_t)grow * Ncols + bn * 128 + l32 * 4) =
                        *(const uint4*)&ep32[row * 132 + l32 * 4];
            }
        }
    }
}

/* -------- MFMA flash attention v7: g2l16 K + XOR-swizzled LDS, 5 blk/CU --
   vs v6:
   - K staged by global_load_lds DIRECT into Kt[2][64][64] (no kreg, no
     LDS writes). Linear LDS dest + SOURCE-side XOR swizzle: lane fetches
     global chunk (l&7)^(l>>3) so the linear write realizes
     Kt[r][c ^ (r&7)] (chunk = 8 bf16). Reads use c' = c ^ (row&7):
     2-way bank aliasing (free).
   - K(t+1) issued AFTER the barrier (all waves past it -> no reader of
     buf^1 remains -> no WAR race), hidden under compute(t), drained by
     next pre-barrier vmcnt(0). Never exposed.
   - Vt[2][64][64] unpadded: scatter writes at vcol ^ (j<<3) (row&7 == j),
     reads at chunk lq ^ (row&7): both 2-way free.
   - Lw removed: final 1/l via __shfl (value for q-local lq*4+r lives at
     lane lq*4+r after the quad-reduce).
   LDS = exactly 32768 B; __launch_bounds__(256,5) -> 5 blocks/CU.       */
__global__ __launch_bounds__(256, 5)
void attn_mfma(const u16* __restrict__ qkv, u16* __restrict__ out)
{
    __shared__ __align__(16) u16 Kt[2][64][64];
    __shared__ __align__(16) u16 Vt[2][64][64];

    const int l   = blockIdx.x;
    const int xcd = l & 7;
    const int j0  = l >> 3;            /* 0..107 */
    const int bh  = xcd * 12 + j0 / 9; /* 12 heads per XCD */
    const int b  = bh / H_, h = bh % H_;
    const int q0 = (j0 % 9) * 128;
    const int tid  = threadIdx.x;
    const int wave = tid >> 6, lane = tid & 63;
    const int lm = lane & 15, lq = lane >> 4;
    const int qw = q0 + wave * 32;

    /* key -> kslot permutation: key = 32a+16b+4c+r  ->  32a+8c+4b+r */
    const int vcol = (lane & 35) | ((lane & 12) << 1) | ((lane & 16) >> 2);

    /* K g2l16 source swizzle: lane covers row l>>3 (of 8), chunk (l&7)^(l>>3) */
    const int krlane = lane >> 3;
    const int kclane = (lane & 7) ^ krlane;

    /* Q fragments (B-operand: n=q=lm, k=d=lq*8+j); 1/8 scale already baked */
    bf16x8 qf[2][2];
#pragma unroll
    for (int sq = 0; sq < 2; sq++) {
        int qrow = qw + sq * 16 + lm; if (qrow > N_ - 1) qrow = N_ - 1;
        const u16* qptr = qkv + (size_t)(b * N_ + qrow) * QKVC + h * HD_;
        qf[sq][0] = *(const bf16x8*)(qptr + lq * 8);
        qf[sq][1] = *(const bf16x8*)(qptr + 32 + lq * 8);
    }

    const u16* kgb = qkv + (size_t)b * N_ * QKVC + D_ + h * HD_;
    const u16* vgb = qkv + (size_t)b * N_ * QKVC + 2 * D_ + h * HD_ + wave * 8;

    float l_r[2] = {0.f, 0.f};
    f32x4 o_acc[2][4];
#pragma unroll
    for (int sq = 0; sq < 2; sq++)
#pragma unroll
        for (int t = 0; t < 4; t++)
            o_acc[sq][t] = (f32x4){0.f, 0.f, 0.f, 0.f};

    /* prologue: issue K(0) (g2l16) and V(0) (register) */
    bf16x8 vreg[2];
    {
#pragma unroll
        for (int i = 0; i < 2; i++) {
            int key = wave * 16 + i * 8 + krlane; if (key > N_ - 1) key = N_ - 1;
            g2l16(kgb + (size_t)key * QKVC + kclane * 8, &Kt[0][wave * 16 + i * 8][0]);
        }
        int vr = lane; if (vr > N_ - 1) vr = N_ - 1;
        const u16* p = vgb + (size_t)vr * QKVC;
        vreg[0] = *(const bf16x8*)p;
        vreg[1] = *(const bf16x8*)(p + 32);
    }

    const int kTiles = (N_ + 63) / 64;   /* 17 */
    for (int kt = 0; kt < kTiles; kt++) {
        const int kbase = kt * 64;
        const int buf = kt & 1;

        /* stage V(t): kslot-permuted, XOR-swizzled scatter (row&7 == j) */
#pragma unroll
        for (int pp = 0; pp < 2; pp++) {
            int dg = wave + pp * 4;
#pragma unroll
            for (int j = 0; j < 8; j++)
                Vt[buf][dg * 8 + j][vcol ^ (j << 3)] = (u16)vreg[pp][j];
        }

        /* our K(t) g2l16s landed + V scatter visible; nothing else in flight */
        asm volatile("s_waitcnt vmcnt(0) lgkmcnt(0)" ::: "memory");
        __builtin_amdgcn_s_barrier();

        /* issue next tile's K (buf^1 safe: every wave is past the barrier,
           so no reader of buf^1 remains) and V loads; both hide under
           this tile's compute.                                           */
        if (kt + 1 < kTiles) {
            const int kb = kbase + 64;
#pragma unroll
            for (int i = 0; i < 2; i++) {
                int key = kb + wave * 16 + i * 8 + krlane; if (key > N_ - 1) key = N_ - 1;
                g2l16(kgb + (size_t)key * QKVC + kclane * 8, &Kt[buf ^ 1][wave * 16 + i * 8][0]);
            }
            int vr = kb + lane; if (vr > N_ - 1) vr = N_ - 1;
            const u16* p = vgb + (size_t)vr * QKVC;
            vreg[0] = *(const bf16x8*)p;
            vreg[1] = *(const bf16x8*)(p + 32);
        }

        /* S^T = K (Q/8)^T : A = Kt row-frags (swizzled chunk), B = Q regs.
           C: col=lm=q_local, row=lq*4+r -> key st*16+lq*4+r.              */
        f32x4 sc[2][4];
        __builtin_amdgcn_s_setprio(1);
#pragma unroll
        for (int st = 0; st < 4; st++) {
            const int krow = st * 16 + lm;
            const int c0 = lq ^ (krow & 7);
            bf16x8 kf0 = *(const bf16x8*)&Kt[buf][krow][c0 * 8];
            bf16x8 kf1 = *(const bf16x8*)&Kt[buf][krow][(c0 ^ 4) * 8];
#pragma unroll
            for (int sq = 0; sq < 2; sq++) {
                f32x4 s4 = (f32x4){0.f, 0.f, 0.f, 0.f};
                s4 = __builtin_amdgcn_mfma_f32_16x16x32_bf16(kf0, qf[sq][0], s4, 0, 0, 0);
                s4 = __builtin_amdgcn_mfma_f32_16x16x32_bf16(kf1, qf[sq][1], s4, 0, 0, 0);
                sc[sq][st] = s4;
            }
        }
        __builtin_amdgcn_s_setprio(0);

        /* softmax (fixed max 0) + in-register pack straight into the PV
           A-operand order (kslot permutation makes layouts coincide).   */
        const bool lastT = (kt == kTiles - 1);
        bf16x8 pa[2][2];
#pragma unroll
        for (int sq = 0; sq < 2; sq++) {
            union { bf16x8 v; unsigned int u[4]; } pk0, pk1;
#pragma unroll
            for (int st = 0; st < 4; st++) {
                float p0 = __expf(sc[sq][st][0]);
                float p1 = __expf(sc[sq][st][1]);
                float p2 = __expf(sc[sq][st][2]);
                float p3 = __expf(sc[sq][st][3]);
                if (lastT) {
                    const int keyb = kbase + st * 16 + lq * 4;
                    if (keyb + 0 >= N_) p0 = 0.f;
                    if (keyb + 1 >= N_) p1 = 0.f;
                    if (keyb + 2 >= N_) p2 = 0.f;
                    if (keyb + 3 >= N_) p3 = 0.f;
                }
                l_r[sq] += (p0 + p1) + (p2 + p3);
                unsigned int lo = cvtpk(p0, p1);
                unsigned int hi = cvtpk(p2, p3);
                if      (st == 0) { pk0.u[0] = lo; pk0.u[1] = hi; }
                else if (st == 1) { pk0.u[2] = lo; pk0.u[3] = hi; }
                else if (st == 2) { pk1.u[0] = lo; pk1.u[1] = hi; }
                else              { pk1.u[2] = lo; pk1.u[3] = hi; }
            }
            pa[sq][0] = pk0.v; pa[sq][1] = pk1.v;
        }

        /* PV: A = packed P regs, B = Vt rows (swizzled chunk, kslot cols) */
        __builtin_amdgcn_s_setprio(1);
#pragma unroll
        for (int nt = 0; nt < 4; nt++) {
            const int vrow = nt * 16 + lm;
            const int d0 = lq ^ (vrow & 7);
            bf16x8 vb0 = *(const bf16x8*)&Vt[buf][vrow][d0 * 8];
            bf16x8 vb1 = *(const bf16x8*)&Vt[buf][vrow][(d0 ^ 4) * 8];
#pragma unroll
            for (int sq = 0; sq < 2; sq++) {
                o_acc[sq][nt] = __builtin_amdgcn_mfma_f32_16x16x32_bf16(pa[sq][0], vb0, o_acc[sq][nt], 0, 0, 0);
                o_acc[sq][nt] = __builtin_amdgcn_mfma_f32_16x16x32_bf16(pa[sq][1], vb1, o_acc[sq][nt], 0, 0, 0);
            }
        }
        __builtin_amdgcn_s_setprio(0);
    }

    /* l: quad-reduce; every lane then holds l_full for q = sq*16 + lm.
       Consumer (q = sq*16 + lq*4 + r) pulls it from lane lq*4+r.        */
    float lfull[2];
#pragma unroll
    for (int sq = 0; sq < 2; sq++) {
        float l2 = l_r[sq];
        l2 += __shfl_xor(l2, 16);
        l2 += __shfl_xor(l2, 32);
        lfull[sq] = l2;
    }

    /* store: O layout col=d=nt*16+lm, row=q=sq*16+lq*4+r */
#pragma unroll
    for (int sq = 0; sq < 2; sq++)
#pragma unroll
        for (int r = 0; r < 4; r++) {
            int q = qw + sq * 16 + lq * 4 + r;
            if (q < N_) {
                float inv = 1.0f / __shfl(lfull[sq], lq * 4 + r);
                u16* orow = out + (size_t)(b * N_ + q) * D_ + h * HD_ + lm;
#pragma unroll
                for (int nt = 0; nt < 4; nt++)
                    orow[nt * 16] = f2bf(o_acc[sq][nt][r] * inv);
            }
        }
}

extern "C" void kernel_launch(void* const* d_in, const int* in_sizes, int n_in,
                              void* d_out, int out_size, void* d_ws, size_t ws_size,
                              hipStream_t stream)
{
    const float* x      = (const float*)d_in[0];
    const float* ln_g   = (const float*)d_in[1];
    const float* ln_b   = (const float*)d_in[2];
    const float* w_qkv  = (const float*)d_in[3];
    const float* w_proj = (const float*)d_in[4];
    const float* b_proj = (const float*)d_in[5];

    u16* wqkv_b  = (u16*)d_ws;                         /* 2304*768  */
    u16* wproj_b = wqkv_b + (size_t)QKVC * D_;         /* 768*768   */
    u16* xn      = wproj_b + (size_t)D_ * D_;          /* M_PAD*768 */
    u16* qkv     = xn + (size_t)M_PAD * D_;            /* M_PAD*2304 */
    u16* attno   = xn;                                 /* alias (xn dead after QKV GEMM) */

    /* fused LN (wave/row) + weight convert: 2050 + 2304 blocks */
    ln_f2b_kernel<<<LN_BLK + (QKVC * D_ + D_ * D_) / 1024, 256, 0, stream>>>(
        x, ln_g, ln_b, xn, w_qkv, wqkv_b, w_proj, wproj_b);

    /* QKV GEMM: BM=65, BN=18; 4x2 XCD patches of 17x9 -> 1224 blocks */
    gemm_bt<u16, true><<<1224, 256, 0, stream>>>(
        xn, wqkv_b, qkv, nullptr, M_REAL, QKVC, D_,
        65, 18, 17, 9, 2);

    /* attention: 8 XCDs x 12 heads x 9 q-tiles = 864 blocks */
    attn_mfma<<<864, 256, 0, stream>>>(qkv, attno);

    /* proj GEMM: BM=65, BN=6; 8x1 XCD patches of 9x6 -> 432 blocks */
    gemm_bt<float, false><<<432, 256, 0, stream>>>(
        attno, wproj_b, (float*)d_out, b_proj, M_REAL, D_, D_,
        65, 6, 9, 6, 1);
}

// Round 6
// 211.737 us; speedup vs baseline: 1.3656x; 1.3656x over previous
//
#include <hip/hip_runtime.h>
#include <hip/hip_bf16.h>

typedef unsigned short u16;

#define B_      8
#define N_      1025
#define D_      768
#define H_      12
#define HD_     64
#define M_REAL  (B_ * N_)      /* 8200 rows */
#define M_PAD   8320           /* 65 * 128 */
#define QKVC    (3 * D_)       /* 2304 */
#define LN_BLK  (M_REAL / 4)   /* 2050 wave-per-row blocks */

typedef __attribute__((ext_vector_type(8))) short bf16x8;
typedef __attribute__((ext_vector_type(4))) float f32x4;

static __device__ __forceinline__ float bf2f(u16 u) {
    union { unsigned int i; float f; } v; v.i = ((unsigned int)u) << 16; return v.f;
}
static __device__ __forceinline__ u16 f2bf(float f) {
    union { float f; unsigned int i; } v; v.f = f;
    unsigned int x = v.i;
    return (u16)((x + 0x7fffu + ((x >> 16) & 1u)) >> 16);   /* RNE */
}
static __device__ __forceinline__ unsigned int cvtpk(float a, float b) {
    unsigned int r;
    asm volatile("v_cvt_pk_bf16_f32 %0, %1, %2" : "=v"(r) : "v"(a), "v"(b));
    return r;   /* lo = bf16(a), hi = bf16(b) */
}

/* async global->LDS, 16B per lane; LDS dest = wave-uniform base + lane*16 */
static __device__ __forceinline__ void g2l16(const u16* g, u16* l) {
    __builtin_amdgcn_global_load_lds(
        (const __attribute__((address_space(1))) unsigned int*)g,
        (__attribute__((address_space(3))) unsigned int*)l, 16, 0, 0);
}

/* ------- fused LayerNorm (wave per row) + fp32->bf16 weight convert ------- */
__global__ __launch_bounds__(256)
void ln_f2b_kernel(const float* __restrict__ x, const float* __restrict__ g,
                   const float* __restrict__ bvec, u16* __restrict__ xn,
                   const float* __restrict__ wq, u16* __restrict__ wqb,
                   const float* __restrict__ wp, u16* __restrict__ wpb)
{
    const int tid = threadIdx.x;
    if (blockIdx.x >= LN_BLK) {
        /* weight convert: 1024 elems per block */
        int i = (blockIdx.x - LN_BLK) * 1024 + tid * 4;
        const float* src; u16* dst;
        if (i < QKVC * D_) { src = wq + i; dst = wqb + i; }
        else { src = wp + (i - QKVC * D_); dst = wpb + (i - QKVC * D_); }
        float4 v = *(const float4*)src;
        dst[0] = f2bf(v.x); dst[1] = f2bf(v.y);
        dst[2] = f2bf(v.z); dst[3] = f2bf(v.w);
        return;
    }
    /* one wave per row: 768 = 3 * 64 lanes * float4, shuffle reduce, no barrier */
    const int wave = tid >> 6, lane = tid & 63;
    const int row  = blockIdx.x * 4 + wave;          /* < 8200 exactly */
    const float* xr = x + (size_t)row * D_;
    float4 v[3];
    float s = 0.f, ss = 0.f;
#pragma unroll
    for (int j = 0; j < 3; j++) {
        float4 t = *(const float4*)&xr[j * 256 + lane * 4];
        v[j] = t;
        s  += (t.x + t.y) + (t.z + t.w);
        ss += (t.x * t.x + t.y * t.y) + (t.z * t.z + t.w * t.w);
    }
#pragma unroll
    for (int off = 1; off < 64; off <<= 1) {
        s  += __shfl_xor(s,  off);
        ss += __shfl_xor(ss, off);
    }
    const float mean = s * (1.0f / D_);
    const float var  = ss * (1.0f / D_) - mean * mean;
    const float rs   = rsqrtf(var + 1e-5f);
    u16* outr = xn + (size_t)row * D_;
#pragma unroll
    for (int j = 0; j < 3; j++) {
        int c = j * 256 + lane * 4;
        float4 g4 = *(const float4*)&g[c];
        float4 b4 = *(const float4*)&bvec[c];
        u16 o[4];
        o[0] = f2bf((v[j].x - mean) * rs * g4.x + b4.x);
        o[1] = f2bf((v[j].y - mean) * rs * g4.y + b4.y);
        o[2] = f2bf((v[j].z - mean) * rs * g4.z + b4.z);
        o[3] = f2bf((v[j].w - mean) * rs * g4.w + b4.w);
        *(uint2*)&outr[c] = *(const uint2*)o;
    }
}

/* -------- GEMM: C[m][n] = sum_k A[m][k] * B[n][k] (+bias fp32) --------
   r3 version (measured 61.4us QKV): 128x128 tile, BK=32, 4 waves (2x2),
   counted-vmcnt pipeline, 34816 B LDS, pad-based epilogues.             */
template <typename OutT, bool ROPE>
__global__ __launch_bounds__(256)
void gemm_bt(const u16* __restrict__ A, const u16* __restrict__ B,
             OutT* __restrict__ C, const float* __restrict__ bias,
             int M_real, int Ncols, int K,
             int BM, int BN, int gh, int gw, int PC)
{
    const int l   = blockIdx.x;
    const int xcd = l & 7;
    const int i0  = l >> 3;
    const int pr  = xcd / PC, pc = xcd % PC;
    const int bm  = pr * gh + (i0 % gh);
    const int bn  = pc * gw + (i0 / gh);
    if (bm >= BM || bn >= BN) return;

    __shared__ __align__(16) unsigned char smem[34816];
    u16* As0 = (u16*)smem;              /* 128 x 32 */
    u16* Bs0 = (u16*)(smem + 8192);
    u16*   ep16 = (u16*)smem;           /* 128 x 136 (pad 8) */
    float* ep32 = (float*)smem;         /* 64 x 132 (pad 4)  */

    const int tid  = threadIdx.x;
    const int wave = tid >> 6, lane = tid & 63;
    const int wm   = (wave >> 1) * 64, wn = (wave & 1) * 64;
    const int lrow = lane & 15, lq = lane >> 4;
    const int lrow4 = lane >> 2, lchunk = lane & 3;

    int ar0 = bm * 128 + wave * 16 + lrow4;       if (ar0 >= M_real) ar0 = M_real - 1;
    int ar1 = bm * 128 + (wave + 4) * 16 + lrow4; if (ar1 >= M_real) ar1 = M_real - 1;
    const u16* apg0 = A + (size_t)ar0 * K + lchunk * 8;
    const u16* apg1 = A + (size_t)ar1 * K + lchunk * 8;
    const u16* bpg0 = B + (size_t)(bn * 128 + wave * 16 + lrow4) * K + lchunk * 8;
    const u16* bpg1 = B + (size_t)(bn * 128 + (wave + 4) * 16 + lrow4) * K + lchunk * 8;
    u16* asl0 = As0 + wave * 512;       u16* asl1 = As0 + (wave + 4) * 512;
    u16* bsl0 = Bs0 + wave * 512;       u16* bsl1 = Bs0 + (wave + 4) * 512;
    const int bufoff = 8192;

    f32x4 acc[4][4];
#pragma unroll
    for (int i = 0; i < 4; i++)
#pragma unroll
        for (int j = 0; j < 4; j++)
            acc[i][j] = (f32x4){0.f, 0.f, 0.f, 0.f};

    g2l16(apg0, asl0); g2l16(apg1, asl1);
    g2l16(bpg0, bsl0); g2l16(bpg1, bsl1);

    const int kTiles = K / 32;
    for (int kt = 0; kt < kTiles; kt++) {
        const int cur = kt & 1;
        /* issue next tile BEFORE the wait: its 4 loads stay in flight
           across the barrier (counted vmcnt, no full drain).           */
        if (kt + 1 < kTiles) {
            const int k1 = (kt + 1) * 32;
            const int no = (cur ^ 1) * bufoff;
            g2l16(apg0 + k1, asl0 + no); g2l16(apg1 + k1, asl1 + no);
            g2l16(bpg0 + k1, bsl0 + no); g2l16(bpg1 + k1, bsl1 + no);
            asm volatile("s_waitcnt vmcnt(4)" ::: "memory");
        } else {
            asm volatile("s_waitcnt vmcnt(0)" ::: "memory");
        }
        __builtin_amdgcn_s_barrier();      /* current tile visible to all */

        const u16* Asr = As0 + cur * bufoff;
        const u16* Bsr = Bs0 + cur * bufoff;
        bf16x8 af[4], bfr[4];
#pragma unroll
        for (int i = 0; i < 4; i++) {
            af[i]  = *(const bf16x8*)&Asr[(wm + i * 16 + lrow) * 32 + lq * 8];
            bfr[i] = *(const bf16x8*)&Bsr[(wn + i * 16 + lrow) * 32 + lq * 8];
        }
        __builtin_amdgcn_s_setprio(1);
#pragma unroll
        for (int i = 0; i < 4; i++)
#pragma unroll
            for (int j = 0; j < 4; j++)
                acc[i][j] = __builtin_amdgcn_mfma_f32_16x16x32_bf16(af[i], bfr[j], acc[i][j], 0, 0, 0);
        __builtin_amdgcn_s_setprio(0);
        /* all waves done reading buf cur before iter kt+1 overwrites it */
        __builtin_amdgcn_s_barrier();
    }
    __syncthreads();

    if constexpr (sizeof(OutT) == 2) {
#pragma unroll
        for (int j = 0; j < 4; j++) {
            int gcol = bn * 128 + wn + j * 16 + lrow;
            float bv = bias ? bias[gcol] : 0.f;
            int qk = gcol / D_;
            int dh = gcol & 63;
            int half = dh >> 5, ii = (dh & 31) >> 1;
            float sgn = (dh & 1) ? 1.f : -1.f;
            float invf = exp2f(-(float)ii * 0.8304820237218406f);
#pragma unroll
            for (int i = 0; i < 4; i++)
#pragma unroll
                for (int r = 0; r < 4; r++) {
                    int grow = bm * 128 + wm + i * 16 + lq * 4 + r;
                    float val = acc[i][j][r] + bv;
                    if constexpr (ROPE) {
                        if (qk < 2) {
                            float partner = __shfl_xor(val, 1);
                            int n = grow % N_;
                            int pl = n - 1;
                            int pos = (n == 0) ? 0 : (half ? (pl & 31) : (pl >> 5));
                            float ang = (float)pos * invf;
                            val = val * __cosf(ang) + sgn * partner * __sinf(ang);
                            if (qk == 0) val *= 0.125f;   /* fold 1/sqrt(hd) into Q (exact) */
                        }
                    }
                    ep16[(wm + i * 16 + lq * 4 + r) * 136 + wn + j * 16 + lrow] = f2bf(val);
                }
        }
        __syncthreads();
#pragma unroll
        for (int c = 0; c < 8; c++) {
            int idx = tid + c * 256;
            int row = idx >> 4, l16 = idx & 15;
            int grow = bm * 128 + row;
            if (grow < M_real)
                *(uint4*)((u16*)C + (size_t)grow * Ncols + bn * 128 + l16 * 8) =
                    *(const uint4*)&ep16[row * 136 + l16 * 8];
        }
    } else {
#pragma unroll
        for (int s = 0; s < 2; s++) {
            if (s) __syncthreads();
            if (wm == s * 64) {
#pragma unroll
                for (int j = 0; j < 4; j++) {
                    int gcol = bn * 128 + wn + j * 16 + lrow;
                    float bv = bias ? bias[gcol] : 0.f;
#pragma unroll
                    for (int i = 0; i < 4; i++)
#pragma unroll
                        for (int r = 0; r < 4; r++)
                            ep32[(i * 16 + lq * 4 + r) * 132 + wn + j * 16 + lrow] =
                                acc[i][j][r] + bv;
                }
            }
            __syncthreads();
#pragma unroll
            for (int c = 0; c < 8; c++) {
                int idx = tid + c * 256;
                int row = idx >> 5, l32 = idx & 31;
                int grow = bm * 128 + s * 64 + row;
                if (grow < M_real)
                    *(uint4*)((float*)C + (size_t)grow * Ncols + bn * 128 + l32 * 4) =
                        *(const uint4*)&ep32[row * 132 + l32 * 4];
            }
        }
    }
}

/* -------- MFMA flash attention v8: v6 structure + LDS shrink to 32 KB ----
   = v6 (kreg/vreg register staging, 72 VGPR, measured ~55us) with ONLY:
   - pads removed via XOR-chunk swizzle (chunk ^= row&7 on both Kt and Vt;
     bank pattern identical to the +8 pad; correctness verified in the
     passing v7 run).
   - Lw LDS broadcast replaced by __shfl (verified in v7).
   LDS = 2*64*64*2B*2 = 32768 B exactly -> 5 blocks/CU when VGPR <= 102.
   NO __launch_bounds__ min-waves arg (the v7 spill poison).             */
__global__ __launch_bounds__(256)
void attn_mfma(const u16* __restrict__ qkv, u16* __restrict__ out)
{
    __shared__ __align__(16) u16 Kt[2][64][64];
    __shared__ __align__(16) u16 Vt[2][64][64];

    const int l   = blockIdx.x;
    const int xcd = l & 7;
    const int j0  = l >> 3;            /* 0..107 */
    const int bh  = xcd * 12 + j0 / 9; /* 12 heads per XCD */
    const int b  = bh / H_, h = bh % H_;
    const int q0 = (j0 % 9) * 128;
    const int tid  = threadIdx.x;
    const int wave = tid >> 6, lane = tid & 63;
    const int lm = lane & 15, lq = lane >> 4;
    const int qw = q0 + wave * 32;

    /* key -> kslot permutation: key = 32a+16b+4c+r  ->  32a+8c+4b+r */
    const int vcol = (lane & 35) | ((lane & 12) << 1) | ((lane & 16) >> 2);

    /* Q fragments (B-operand: n=q=lm, k=d=lq*8+j); 1/8 scale already baked */
    bf16x8 qf[2][2];
#pragma unroll
    for (int sq = 0; sq < 2; sq++) {
        int qrow = qw + sq * 16 + lm; if (qrow > N_ - 1) qrow = N_ - 1;
        const u16* qptr = qkv + (size_t)(b * N_ + qrow) * QKVC + h * HD_;
        qf[sq][0] = *(const bf16x8*)(qptr + lq * 8);
        qf[sq][1] = *(const bf16x8*)(qptr + 32 + lq * 8);
    }

    float l_r[2] = {0.f, 0.f};
    f32x4 o_acc[2][4];
#pragma unroll
    for (int sq = 0; sq < 2; sq++)
#pragma unroll
        for (int t = 0; t < 4; t++)
            o_acc[sq][t] = (f32x4){0.f, 0.f, 0.f, 0.f};

    /* prefetch K,V tile 0 into registers (lane = key row, wave covers d-groups) */
    bf16x8 kreg[2], vreg[2];
    {
        int krow = lane; if (krow > N_ - 1) krow = N_ - 1;
        const u16* kvp = qkv + (size_t)(b * N_ + krow) * QKVC + h * HD_;
#pragma unroll
        for (int p = 0; p < 2; p++) {
            int dg = wave + p * 4;
            kreg[p] = *(const bf16x8*)(kvp + D_ + dg * 8);
            vreg[p] = *(const bf16x8*)(kvp + 2 * D_ + dg * 8);
        }
    }

    const int kTiles = (N_ + 63) / 64;   /* 17 */
    for (int kt = 0; kt < kTiles; kt++) {
        const int kbase = kt * 64;
        const int buf = kt & 1;

        /* stage K (row-major, chunk XOR row&7) and V (transposed, kslot
           columns, chunk XOR row&7)                                      */
#pragma unroll
        for (int pp = 0; pp < 2; pp++) {
            int dg = wave + pp * 4;
            *(bf16x8*)&Kt[buf][lane][(dg ^ (lane & 7)) * 8] = kreg[pp];
#pragma unroll
            for (int j = 0; j < 8; j++)
                Vt[buf][dg * 8 + j][vcol ^ (j << 3)] = (u16)vreg[pp][j];
        }

        /* register prefetch of next K,V tile (stays in flight across barrier) */
        if (kt + 1 < kTiles) {
            int krow = kbase + 64 + lane; if (krow > N_ - 1) krow = N_ - 1;
            const u16* kvp = qkv + (size_t)(b * N_ + krow) * QKVC + h * HD_;
#pragma unroll
            for (int pp = 0; pp < 2; pp++) {
                int dg = wave + pp * 4;
                kreg[pp] = *(const bf16x8*)(kvp + D_ + dg * 8);
                vreg[pp] = *(const bf16x8*)(kvp + 2 * D_ + dg * 8);
            }
        }

        /* LDS writes visible to all waves; global prefetch NOT drained */
        asm volatile("s_waitcnt lgkmcnt(0)" ::: "memory");
        __builtin_amdgcn_s_barrier();

        /* S^T = K (Q/8)^T : A = Kt row-frags (swizzled chunk), B = Q regs.
           C: col=lm=q_local, row=lq*4+r -> key st*16+lq*4+r.              */
        f32x4 sc[2][4];
        __builtin_amdgcn_s_setprio(1);
#pragma unroll
        for (int st = 0; st < 4; st++) {
            const int krow = st * 16 + lm;
            const int c0 = lq ^ (krow & 7);
            bf16x8 kf0 = *(const bf16x8*)&Kt[buf][krow][c0 * 8];
            bf16x8 kf1 = *(const bf16x8*)&Kt[buf][krow][(c0 ^ 4) * 8];
#pragma unroll
            for (int sq = 0; sq < 2; sq++) {
                f32x4 s4 = (f32x4){0.f, 0.f, 0.f, 0.f};
                s4 = __builtin_amdgcn_mfma_f32_16x16x32_bf16(kf0, qf[sq][0], s4, 0, 0, 0);
                s4 = __builtin_amdgcn_mfma_f32_16x16x32_bf16(kf1, qf[sq][1], s4, 0, 0, 0);
                sc[sq][st] = s4;
            }
        }
        __builtin_amdgcn_s_setprio(0);

        /* softmax (fixed max 0) + in-register pack straight into the PV
           A-operand order (kslot permutation makes layouts coincide).   */
        const bool lastT = (kt == kTiles - 1);
        bf16x8 pa[2][2];
#pragma unroll
        for (int sq = 0; sq < 2; sq++) {
            union { bf16x8 v; unsigned int u[4]; } pk0, pk1;
#pragma unroll
            for (int st = 0; st < 4; st++) {
                float p0 = __expf(sc[sq][st][0]);
                float p1 = __expf(sc[sq][st][1]);
                float p2 = __expf(sc[sq][st][2]);
                float p3 = __expf(sc[sq][st][3]);
                if (lastT) {
                    const int keyb = kbase + st * 16 + lq * 4;
                    if (keyb + 0 >= N_) p0 = 0.f;
                    if (keyb + 1 >= N_) p1 = 0.f;
                    if (keyb + 2 >= N_) p2 = 0.f;
                    if (keyb + 3 >= N_) p3 = 0.f;
                }
                l_r[sq] += (p0 + p1) + (p2 + p3);
                unsigned int lo = cvtpk(p0, p1);
                unsigned int hi = cvtpk(p2, p3);
                if      (st == 0) { pk0.u[0] = lo; pk0.u[1] = hi; }
                else if (st == 1) { pk0.u[2] = lo; pk0.u[3] = hi; }
                else if (st == 2) { pk1.u[0] = lo; pk1.u[1] = hi; }
                else              { pk1.u[2] = lo; pk1.u[3] = hi; }
            }
            pa[sq][0] = pk0.v; pa[sq][1] = pk1.v;
        }

        /* PV: A = packed P regs, B = Vt rows (swizzled chunk, kslot cols) */
        __builtin_amdgcn_s_setprio(1);
#pragma unroll
        for (int nt = 0; nt < 4; nt++) {
            const int vrow = nt * 16 + lm;
            const int d0 = lq ^ (vrow & 7);
            bf16x8 vb0 = *(const bf16x8*)&Vt[buf][vrow][d0 * 8];
            bf16x8 vb1 = *(const bf16x8*)&Vt[buf][vrow][(d0 ^ 4) * 8];
#pragma unroll
            for (int sq = 0; sq < 2; sq++) {
                o_acc[sq][nt] = __builtin_amdgcn_mfma_f32_16x16x32_bf16(pa[sq][0], vb0, o_acc[sq][nt], 0, 0, 0);
                o_acc[sq][nt] = __builtin_amdgcn_mfma_f32_16x16x32_bf16(pa[sq][1], vb1, o_acc[sq][nt], 0, 0, 0);
            }
        }
        __builtin_amdgcn_s_setprio(0);
    }

    /* l: quad-reduce; every lane then holds l_full for q = sq*16 + lm.
       Consumer (q = sq*16 + lq*4 + r) pulls it from lane lq*4+r.        */
    float lfull[2];
#pragma unroll
    for (int sq = 0; sq < 2; sq++) {
        float l2 = l_r[sq];
        l2 += __shfl_xor(l2, 16);
        l2 += __shfl_xor(l2, 32);
        lfull[sq] = l2;
    }

    /* store: O layout col=d=nt*16+lm, row=q=sq*16+lq*4+r */
#pragma unroll
    for (int sq = 0; sq < 2; sq++)
#pragma unroll
        for (int r = 0; r < 4; r++) {
            int q = qw + sq * 16 + lq * 4 + r;
            if (q < N_) {
                float inv = 1.0f / __shfl(lfull[sq], lq * 4 + r);
                u16* orow = out + (size_t)(b * N_ + q) * D_ + h * HD_ + lm;
#pragma unroll
                for (int nt = 0; nt < 4; nt++)
                    orow[nt * 16] = f2bf(o_acc[sq][nt][r] * inv);
            }
        }
}

extern "C" void kernel_launch(void* const* d_in, const int* in_sizes, int n_in,
                              void* d_out, int out_size, void* d_ws, size_t ws_size,
                              hipStream_t stream)
{
    const float* x      = (const float*)d_in[0];
    const float* ln_g   = (const float*)d_in[1];
    const float* ln_b   = (const float*)d_in[2];
    const float* w_qkv  = (const float*)d_in[3];
    const float* w_proj = (const float*)d_in[4];
    const float* b_proj = (const float*)d_in[5];

    u16* wqkv_b  = (u16*)d_ws;                         /* 2304*768  */
    u16* wproj_b = wqkv_b + (size_t)QKVC * D_;         /* 768*768   */
    u16* xn      = wproj_b + (size_t)D_ * D_;          /* M_PAD*768 */
    u16* qkv     = xn + (size_t)M_PAD * D_;            /* M_PAD*2304 */
    u16* attno   = xn;                                 /* alias (xn dead after QKV GEMM) */

    /* fused LN (wave/row) + weight convert: 2050 + 2304 blocks */
    ln_f2b_kernel<<<LN_BLK + (QKVC * D_ + D_ * D_) / 1024, 256, 0, stream>>>(
        x, ln_g, ln_b, xn, w_qkv, wqkv_b, w_proj, wproj_b);

    /* QKV GEMM: BM=65, BN=18; 4x2 XCD patches of 17x9 -> 1224 blocks */
    gemm_bt<u16, true><<<1224, 256, 0, stream>>>(
        xn, wqkv_b, qkv, nullptr, M_REAL, QKVC, D_,
        65, 18, 17, 9, 2);

    /* attention: 8 XCDs x 12 heads x 9 q-tiles = 864 blocks */
    attn_mfma<<<864, 256, 0, stream>>>(qkv, attno);

    /* proj GEMM: BM=65, BN=6; 8x1 XCD patches of 9x6 -> 432 blocks */
    gemm_bt<float, false><<<432, 256, 0, stream>>>(
        attno, wproj_b, (float*)d_out, b_proj, M_REAL, D_, D_,
        65, 6, 9, 6, 1);
}

// Round 7
// 207.896 us; speedup vs baseline: 1.3909x; 1.0185x over previous
//
#include <hip/hip_runtime.h>
#include <hip/hip_bf16.h>

typedef unsigned short u16;

#define B_      8
#define N_      1025
#define D_      768
#define H_      12
#define HD_     64
#define M_REAL  (B_ * N_)      /* 8200 rows */
#define M_PAD   8320           /* 65 * 128 */
#define QKVC    (3 * D_)       /* 2304 */
#define LN_BLK  (M_REAL / 4)   /* 2050 wave-per-row blocks */

typedef __attribute__((ext_vector_type(8))) short bf16x8;
typedef __attribute__((ext_vector_type(4))) float f32x4;

static __device__ __forceinline__ float bf2f(u16 u) {
    union { unsigned int i; float f; } v; v.i = ((unsigned int)u) << 16; return v.f;
}
static __device__ __forceinline__ u16 f2bf(float f) {
    union { float f; unsigned int i; } v; v.f = f;
    unsigned int x = v.i;
    return (u16)((x + 0x7fffu + ((x >> 16) & 1u)) >> 16);   /* RNE */
}
static __device__ __forceinline__ unsigned int cvtpk(float a, float b) {
    unsigned int r;
    asm volatile("v_cvt_pk_bf16_f32 %0, %1, %2" : "=v"(r) : "v"(a), "v"(b));
    return r;   /* lo = bf16(a), hi = bf16(b) */
}

/* async global->LDS, 16B per lane; LDS dest = wave-uniform base + lane*16 */
static __device__ __forceinline__ void g2l16(const u16* g, u16* l) {
    __builtin_amdgcn_global_load_lds(
        (const __attribute__((address_space(1))) unsigned int*)g,
        (__attribute__((address_space(3))) unsigned int*)l, 16, 0, 0);
}

/* ------- fused LayerNorm (wave per row) + fp32->bf16 weight convert ------- */
__global__ __launch_bounds__(256)
void ln_f2b_kernel(const float* __restrict__ x, const float* __restrict__ g,
                   const float* __restrict__ bvec, u16* __restrict__ xn,
                   const float* __restrict__ wq, u16* __restrict__ wqb,
                   const float* __restrict__ wp, u16* __restrict__ wpb)
{
    const int tid = threadIdx.x;
    if (blockIdx.x >= LN_BLK) {
        /* weight convert: 1024 elems per block */
        int i = (blockIdx.x - LN_BLK) * 1024 + tid * 4;
        const float* src; u16* dst;
        if (i < QKVC * D_) { src = wq + i; dst = wqb + i; }
        else { src = wp + (i - QKVC * D_); dst = wpb + (i - QKVC * D_); }
        float4 v = *(const float4*)src;
        dst[0] = f2bf(v.x); dst[1] = f2bf(v.y);
        dst[2] = f2bf(v.z); dst[3] = f2bf(v.w);
        return;
    }
    /* one wave per row: 768 = 3 * 64 lanes * float4, shuffle reduce, no barrier */
    const int wave = tid >> 6, lane = tid & 63;
    const int row  = blockIdx.x * 4 + wave;          /* < 8200 exactly */
    const float* xr = x + (size_t)row * D_;
    float4 v[3];
    float s = 0.f, ss = 0.f;
#pragma unroll
    for (int j = 0; j < 3; j++) {
        float4 t = *(const float4*)&xr[j * 256 + lane * 4];
        v[j] = t;
        s  += (t.x + t.y) + (t.z + t.w);
        ss += (t.x * t.x + t.y * t.y) + (t.z * t.z + t.w * t.w);
    }
#pragma unroll
    for (int off = 1; off < 64; off <<= 1) {
        s  += __shfl_xor(s,  off);
        ss += __shfl_xor(ss, off);
    }
    const float mean = s * (1.0f / D_);
    const float var  = ss * (1.0f / D_) - mean * mean;
    const float rs   = rsqrtf(var + 1e-5f);
    u16* outr = xn + (size_t)row * D_;
#pragma unroll
    for (int j = 0; j < 3; j++) {
        int c = j * 256 + lane * 4;
        float4 g4 = *(const float4*)&g[c];
        float4 b4 = *(const float4*)&bvec[c];
        u16 o[4];
        o[0] = f2bf((v[j].x - mean) * rs * g4.x + b4.x);
        o[1] = f2bf((v[j].y - mean) * rs * g4.y + b4.y);
        o[2] = f2bf((v[j].z - mean) * rs * g4.z + b4.z);
        o[3] = f2bf((v[j].w - mean) * rs * g4.w + b4.w);
        *(uint2*)&outr[c] = *(const uint2*)o;
    }
}

/* -------- GEMM: C[m][n] = sum_k A[m][k] * B[n][k] (+bias fp32) --------
   r3 version (measured 61.4us QKV): 128x128 tile, BK=32, 4 waves (2x2),
   counted-vmcnt pipeline, 34816 B LDS, pad-based epilogues.             */
template <typename OutT, bool ROPE>
__global__ __launch_bounds__(256)
void gemm_bt(const u16* __restrict__ A, const u16* __restrict__ B,
             OutT* __restrict__ C, const float* __restrict__ bias,
             int M_real, int Ncols, int K,
             int BM, int BN, int gh, int gw, int PC)
{
    const int l   = blockIdx.x;
    const int xcd = l & 7;
    const int i0  = l >> 3;
    const int pr  = xcd / PC, pc = xcd % PC;
    const int bm  = pr * gh + (i0 % gh);
    const int bn  = pc * gw + (i0 / gh);
    if (bm >= BM || bn >= BN) return;

    __shared__ __align__(16) unsigned char smem[34816];
    u16* As0 = (u16*)smem;              /* 128 x 32 */
    u16* Bs0 = (u16*)(smem + 8192);
    u16*   ep16 = (u16*)smem;           /* 128 x 136 (pad 8) */
    float* ep32 = (float*)smem;         /* 64 x 132 (pad 4)  */

    const int tid  = threadIdx.x;
    const int wave = tid >> 6, lane = tid & 63;
    const int wm   = (wave >> 1) * 64, wn = (wave & 1) * 64;
    const int lrow = lane & 15, lq = lane >> 4;
    const int lrow4 = lane >> 2, lchunk = lane & 3;

    int ar0 = bm * 128 + wave * 16 + lrow4;       if (ar0 >= M_real) ar0 = M_real - 1;
    int ar1 = bm * 128 + (wave + 4) * 16 + lrow4; if (ar1 >= M_real) ar1 = M_real - 1;
    const u16* apg0 = A + (size_t)ar0 * K + lchunk * 8;
    const u16* apg1 = A + (size_t)ar1 * K + lchunk * 8;
    const u16* bpg0 = B + (size_t)(bn * 128 + wave * 16 + lrow4) * K + lchunk * 8;
    const u16* bpg1 = B + (size_t)(bn * 128 + (wave + 4) * 16 + lrow4) * K + lchunk * 8;
    u16* asl0 = As0 + wave * 512;       u16* asl1 = As0 + (wave + 4) * 512;
    u16* bsl0 = Bs0 + wave * 512;       u16* bsl1 = Bs0 + (wave + 4) * 512;
    const int bufoff = 8192;

    f32x4 acc[4][4];
#pragma unroll
    for (int i = 0; i < 4; i++)
#pragma unroll
        for (int j = 0; j < 4; j++)
            acc[i][j] = (f32x4){0.f, 0.f, 0.f, 0.f};

    g2l16(apg0, asl0); g2l16(apg1, asl1);
    g2l16(bpg0, bsl0); g2l16(bpg1, bsl1);

    const int kTiles = K / 32;
    for (int kt = 0; kt < kTiles; kt++) {
        const int cur = kt & 1;
        /* issue next tile BEFORE the wait: its 4 loads stay in flight
           across the barrier (counted vmcnt, no full drain).           */
        if (kt + 1 < kTiles) {
            const int k1 = (kt + 1) * 32;
            const int no = (cur ^ 1) * bufoff;
            g2l16(apg0 + k1, asl0 + no); g2l16(apg1 + k1, asl1 + no);
            g2l16(bpg0 + k1, bsl0 + no); g2l16(bpg1 + k1, bsl1 + no);
            asm volatile("s_waitcnt vmcnt(4)" ::: "memory");
        } else {
            asm volatile("s_waitcnt vmcnt(0)" ::: "memory");
        }
        __builtin_amdgcn_s_barrier();      /* current tile visible to all */

        const u16* Asr = As0 + cur * bufoff;
        const u16* Bsr = Bs0 + cur * bufoff;
        bf16x8 af[4], bfr[4];
#pragma unroll
        for (int i = 0; i < 4; i++) {
            af[i]  = *(const bf16x8*)&Asr[(wm + i * 16 + lrow) * 32 + lq * 8];
            bfr[i] = *(const bf16x8*)&Bsr[(wn + i * 16 + lrow) * 32 + lq * 8];
        }
        __builtin_amdgcn_s_setprio(1);
#pragma unroll
        for (int i = 0; i < 4; i++)
#pragma unroll
            for (int j = 0; j < 4; j++)
                acc[i][j] = __builtin_amdgcn_mfma_f32_16x16x32_bf16(af[i], bfr[j], acc[i][j], 0, 0, 0);
        __builtin_amdgcn_s_setprio(0);
        /* all waves done reading buf cur before iter kt+1 overwrites it */
        __builtin_amdgcn_s_barrier();
    }
    __syncthreads();

    if constexpr (sizeof(OutT) == 2) {
#pragma unroll
        for (int j = 0; j < 4; j++) {
            int gcol = bn * 128 + wn + j * 16 + lrow;
            float bv = bias ? bias[gcol] : 0.f;
            int qk = gcol / D_;
            int dh = gcol & 63;
            int half = dh >> 5, ii = (dh & 31) >> 1;
            float sgn = (dh & 1) ? 1.f : -1.f;
            float invf = exp2f(-(float)ii * 0.8304820237218406f);
#pragma unroll
            for (int i = 0; i < 4; i++)
#pragma unroll
                for (int r = 0; r < 4; r++) {
                    int grow = bm * 128 + wm + i * 16 + lq * 4 + r;
                    float val = acc[i][j][r] + bv;
                    if constexpr (ROPE) {
                        if (qk < 2) {
                            float partner = __shfl_xor(val, 1);
                            int n = grow % N_;
                            int pl = n - 1;
                            int pos = (n == 0) ? 0 : (half ? (pl & 31) : (pl >> 5));
                            float ang = (float)pos * invf;
                            val = val * __cosf(ang) + sgn * partner * __sinf(ang);
                            if (qk == 0) val *= 0.125f;   /* fold 1/sqrt(hd) into Q (exact) */
                        }
                    }
                    ep16[(wm + i * 16 + lq * 4 + r) * 136 + wn + j * 16 + lrow] = f2bf(val);
                }
        }
        __syncthreads();
#pragma unroll
        for (int c = 0; c < 8; c++) {
            int idx = tid + c * 256;
            int row = idx >> 4, l16 = idx & 15;
            int grow = bm * 128 + row;
            if (grow < M_real)
                *(uint4*)((u16*)C + (size_t)grow * Ncols + bn * 128 + l16 * 8) =
                    *(const uint4*)&ep16[row * 136 + l16 * 8];
        }
    } else {
#pragma unroll
        for (int s = 0; s < 2; s++) {
            if (s) __syncthreads();
            if (wm == s * 64) {
#pragma unroll
                for (int j = 0; j < 4; j++) {
                    int gcol = bn * 128 + wn + j * 16 + lrow;
                    float bv = bias ? bias[gcol] : 0.f;
#pragma unroll
                    for (int i = 0; i < 4; i++)
#pragma unroll
                        for (int r = 0; r < 4; r++)
                            ep32[(i * 16 + lq * 4 + r) * 132 + wn + j * 16 + lrow] =
                                acc[i][j][r] + bv;
                }
            }
            __syncthreads();
#pragma unroll
            for (int c = 0; c < 8; c++) {
                int idx = tid + c * 256;
                int row = idx >> 5, l32 = idx & 31;
                int grow = bm * 128 + s * 64 + row;
                if (grow < M_real)
                    *(uint4*)((float*)C + (size_t)grow * Ncols + bn * 128 + l32 * 4) =
                        *(const uint4*)&ep32[row * 132 + l32 * 4];
            }
        }
    }
}

/* -------- MFMA flash attention v9: 256 q per block (64 q per wave) -------
   vs v8: each wave now owns 64 queries (sq = 0..3), so the per-tile LDS
   traffic (Kt/Vt reads are IDENTICAL per wave regardless of q-count) is
   amortized over 2x the output: DS-instr per q halves (was the dominant
   pipe, ~34 DS-instr/wave/tile vs ~77cyc MFMA/SIMD). Registers ~200 VGPR
   (o_acc 64 + sc 64 + qf 32 + staging 16) -> ~2 blocks/CU, intentionally
   trading waves for per-wave efficiency. NO __launch_bounds__ cap (v7
   spill lesson). All verified math unchanged: kslot permutation, cvtpk
   pack, fixed-max-0 softmax, XOR-chunk swizzles, N_ masking.
   Grid: 8 XCD x 12 heads x 5 q-tiles(256) = 480 blocks.                  */
__global__ __launch_bounds__(256)
void attn_mfma(const u16* __restrict__ qkv, u16* __restrict__ out)
{
    __shared__ __align__(16) u16 Kt[2][64][64];
    __shared__ __align__(16) u16 Vt[2][64][64];

    const int l   = blockIdx.x;
    const int xcd = l & 7;
    const int j0  = l >> 3;            /* 0..59 */
    const int bh  = xcd * 12 + j0 / 5; /* 12 heads per XCD */
    const int b  = bh / H_, h = bh % H_;
    const int q0 = (j0 % 5) * 256;
    const int tid  = threadIdx.x;
    const int wave = tid >> 6, lane = tid & 63;
    const int lm = lane & 15, lq = lane >> 4;
    const int qw = q0 + wave * 64;     /* 64 queries per wave */

    /* key -> kslot permutation: key = 32a+16b+4c+r  ->  32a+8c+4b+r */
    const int vcol = (lane & 35) | ((lane & 12) << 1) | ((lane & 16) >> 2);

    /* Q fragments (B-operand: n=q=lm, k=d=lq*8+j); 1/8 scale already baked */
    bf16x8 qf[4][2];
#pragma unroll
    for (int sq = 0; sq < 4; sq++) {
        int qrow = qw + sq * 16 + lm; if (qrow > N_ - 1) qrow = N_ - 1;
        const u16* qptr = qkv + (size_t)(b * N_ + qrow) * QKVC + h * HD_;
        qf[sq][0] = *(const bf16x8*)(qptr + lq * 8);
        qf[sq][1] = *(const bf16x8*)(qptr + 32 + lq * 8);
    }

    float l_r[4] = {0.f, 0.f, 0.f, 0.f};
    f32x4 o_acc[4][4];
#pragma unroll
    for (int sq = 0; sq < 4; sq++)
#pragma unroll
        for (int t = 0; t < 4; t++)
            o_acc[sq][t] = (f32x4){0.f, 0.f, 0.f, 0.f};

    /* prefetch K,V tile 0 into registers (lane = key row, wave covers d-groups) */
    bf16x8 kreg[2], vreg[2];
    {
        int krow = lane; if (krow > N_ - 1) krow = N_ - 1;
        const u16* kvp = qkv + (size_t)(b * N_ + krow) * QKVC + h * HD_;
#pragma unroll
        for (int p = 0; p < 2; p++) {
            int dg = wave + p * 4;
            kreg[p] = *(const bf16x8*)(kvp + D_ + dg * 8);
            vreg[p] = *(const bf16x8*)(kvp + 2 * D_ + dg * 8);
        }
    }

    const int kTiles = (N_ + 63) / 64;   /* 17 */
    for (int kt = 0; kt < kTiles; kt++) {
        const int kbase = kt * 64;
        const int buf = kt & 1;

        /* stage K (row-major, chunk XOR row&7) and V (transposed, kslot
           columns, chunk XOR row&7)                                      */
#pragma unroll
        for (int pp = 0; pp < 2; pp++) {
            int dg = wave + pp * 4;
            *(bf16x8*)&Kt[buf][lane][(dg ^ (lane & 7)) * 8] = kreg[pp];
#pragma unroll
            for (int j = 0; j < 8; j++)
                Vt[buf][dg * 8 + j][vcol ^ (j << 3)] = (u16)vreg[pp][j];
        }

        /* register prefetch of next K,V tile (stays in flight across barrier) */
        if (kt + 1 < kTiles) {
            int krow = kbase + 64 + lane; if (krow > N_ - 1) krow = N_ - 1;
            const u16* kvp = qkv + (size_t)(b * N_ + krow) * QKVC + h * HD_;
#pragma unroll
            for (int pp = 0; pp < 2; pp++) {
                int dg = wave + pp * 4;
                kreg[pp] = *(const bf16x8*)(kvp + D_ + dg * 8);
                vreg[pp] = *(const bf16x8*)(kvp + 2 * D_ + dg * 8);
            }
        }

        /* LDS writes visible to all waves; global prefetch NOT drained */
        asm volatile("s_waitcnt lgkmcnt(0)" ::: "memory");
        __builtin_amdgcn_s_barrier();

        /* S^T = K (Q/8)^T : A = Kt row-frags (swizzled chunk), B = Q regs.
           kf read ONCE per st, feeds all 4 sq (the amortization lever).
           C: col=lm=q_local, row=lq*4+r -> key st*16+lq*4+r.              */
        f32x4 sc[4][4];
        __builtin_amdgcn_s_setprio(1);
#pragma unroll
        for (int st = 0; st < 4; st++) {
            const int krow = st * 16 + lm;
            const int c0 = lq ^ (krow & 7);
            bf16x8 kf0 = *(const bf16x8*)&Kt[buf][krow][c0 * 8];
            bf16x8 kf1 = *(const bf16x8*)&Kt[buf][krow][(c0 ^ 4) * 8];
#pragma unroll
            for (int sq = 0; sq < 4; sq++) {
                f32x4 s4 = (f32x4){0.f, 0.f, 0.f, 0.f};
                s4 = __builtin_amdgcn_mfma_f32_16x16x32_bf16(kf0, qf[sq][0], s4, 0, 0, 0);
                s4 = __builtin_amdgcn_mfma_f32_16x16x32_bf16(kf1, qf[sq][1], s4, 0, 0, 0);
                sc[sq][st] = s4;
            }
        }
        __builtin_amdgcn_s_setprio(0);

        /* softmax (fixed max 0) + in-register pack straight into the PV
           A-operand order (kslot permutation makes layouts coincide).   */
        const bool lastT = (kt == kTiles - 1);
        bf16x8 pa[4][2];
#pragma unroll
        for (int sq = 0; sq < 4; sq++) {
            union { bf16x8 v; unsigned int u[4]; } pk0, pk1;
#pragma unroll
            for (int st = 0; st < 4; st++) {
                float p0 = __expf(sc[sq][st][0]);
                float p1 = __expf(sc[sq][st][1]);
                float p2 = __expf(sc[sq][st][2]);
                float p3 = __expf(sc[sq][st][3]);
                if (lastT) {
                    const int keyb = kbase + st * 16 + lq * 4;
                    if (keyb + 0 >= N_) p0 = 0.f;
                    if (keyb + 1 >= N_) p1 = 0.f;
                    if (keyb + 2 >= N_) p2 = 0.f;
                    if (keyb + 3 >= N_) p3 = 0.f;
                }
                l_r[sq] += (p0 + p1) + (p2 + p3);
                unsigned int lo = cvtpk(p0, p1);
                unsigned int hi = cvtpk(p2, p3);
                if      (st == 0) { pk0.u[0] = lo; pk0.u[1] = hi; }
                else if (st == 1) { pk0.u[2] = lo; pk0.u[3] = hi; }
                else if (st == 2) { pk1.u[0] = lo; pk1.u[1] = hi; }
                else              { pk1.u[2] = lo; pk1.u[3] = hi; }
            }
            pa[sq][0] = pk0.v; pa[sq][1] = pk1.v;
        }

        /* PV: A = packed P regs, B = Vt rows (swizzled chunk, kslot cols).
           vb read ONCE per nt, feeds all 4 sq.                           */
        __builtin_amdgcn_s_setprio(1);
#pragma unroll
        for (int nt = 0; nt < 4; nt++) {
            const int vrow = nt * 16 + lm;
            const int d0 = lq ^ (vrow & 7);
            bf16x8 vb0 = *(const bf16x8*)&Vt[buf][vrow][d0 * 8];
            bf16x8 vb1 = *(const bf16x8*)&Vt[buf][vrow][(d0 ^ 4) * 8];
#pragma unroll
            for (int sq = 0; sq < 4; sq++) {
                o_acc[sq][nt] = __builtin_amdgcn_mfma_f32_16x16x32_bf16(pa[sq][0], vb0, o_acc[sq][nt], 0, 0, 0);
                o_acc[sq][nt] = __builtin_amdgcn_mfma_f32_16x16x32_bf16(pa[sq][1], vb1, o_acc[sq][nt], 0, 0, 0);
            }
        }
        __builtin_amdgcn_s_setprio(0);
    }

    /* l: quad-reduce; every lane then holds l_full for q = sq*16 + lm.
       Consumer (q = sq*16 + lq*4 + r) pulls it from lane lq*4+r.        */
    float lfull[4];
#pragma unroll
    for (int sq = 0; sq < 4; sq++) {
        float l2 = l_r[sq];
        l2 += __shfl_xor(l2, 16);
        l2 += __shfl_xor(l2, 32);
        lfull[sq] = l2;
    }

    /* store: O layout col=d=nt*16+lm, row=q=sq*16+lq*4+r */
#pragma unroll
    for (int sq = 0; sq < 4; sq++)
#pragma unroll
        for (int r = 0; r < 4; r++) {
            int q = qw + sq * 16 + lq * 4 + r;
            if (q < N_) {
                float inv = 1.0f / __shfl(lfull[sq], lq * 4 + r);
                u16* orow = out + (size_t)(b * N_ + q) * D_ + h * HD_ + lm;
#pragma unroll
                for (int nt = 0; nt < 4; nt++)
                    orow[nt * 16] = f2bf(o_acc[sq][nt][r] * inv);
            }
        }
}

extern "C" void kernel_launch(void* const* d_in, const int* in_sizes, int n_in,
                              void* d_out, int out_size, void* d_ws, size_t ws_size,
                              hipStream_t stream)
{
    const float* x      = (const float*)d_in[0];
    const float* ln_g   = (const float*)d_in[1];
    const float* ln_b   = (const float*)d_in[2];
    const float* w_qkv  = (const float*)d_in[3];
    const float* w_proj = (const float*)d_in[4];
    const float* b_proj = (const float*)d_in[5];

    u16* wqkv_b  = (u16*)d_ws;                         /* 2304*768  */
    u16* wproj_b = wqkv_b + (size_t)QKVC * D_;         /* 768*768   */
    u16* xn      = wproj_b + (size_t)D_ * D_;          /* M_PAD*768 */
    u16* qkv     = xn + (size_t)M_PAD * D_;            /* M_PAD*2304 */
    u16* attno   = xn;                                 /* alias (xn dead after QKV GEMM) */

    /* fused LN (wave/row) + weight convert: 2050 + 2304 blocks */
    ln_f2b_kernel<<<LN_BLK + (QKVC * D_ + D_ * D_) / 1024, 256, 0, stream>>>(
        x, ln_g, ln_b, xn, w_qkv, wqkv_b, w_proj, wproj_b);

    /* QKV GEMM: BM=65, BN=18; 4x2 XCD patches of 17x9 -> 1224 blocks */
    gemm_bt<u16, true><<<1224, 256, 0, stream>>>(
        xn, wqkv_b, qkv, nullptr, M_REAL, QKVC, D_,
        65, 18, 17, 9, 2);

    /* attention: 8 XCDs x 12 heads x 5 q-tiles(256) = 480 blocks */
    attn_mfma<<<480, 256, 0, stream>>>(qkv, attno);

    /* proj GEMM: BM=65, BN=6; 8x1 XCD patches of 9x6 -> 432 blocks */
    gemm_bt<float, false><<<432, 256, 0, stream>>>(
        attno, wproj_b, (float*)d_out, b_proj, M_REAL, D_, D_,
        65, 6, 9, 6, 1);
}